// Round 3
// 479.225 us; speedup vs baseline: 1.0193x; 1.0193x over previous
//
#include <hip/hip_runtime.h>

// ---------------------------------------------------------------------------
// SE_semantic_Fusion: G = fm@fm.T (bf16 MFMA, split-K over channels),
// row-normalize, z = Gn@y, 6 tiny MLPs -> gates, out = gate * input.
// d_out doubles as scratch for the 33 MB Gram partials (k_apply overwrites
// all of d_out last); d_ws holds only y (256KB) + gates (256KB).
//
// R3 = R1 with compile fixes (nontemporal store via clang ext-vector f32x4;
// launch-site cast for k_apply's out).
// R1 changes vs baseline (489 us):
//  - k_gram: T14 software pipeline (prefetch tile t+1 into regs between
//    mid-barrier and MFMA so HBM latency hides under compute) + native
//    v_cvt_pk_bf16_f32 via __bf16 casts instead of manual RNE bit-trick.
//  - partials layout transposed to [m][plane][n] so k_gates reads one
//    contiguous 256 KB slab per block (was 512-B segments at 64 KB stride).
//  - k_gates phase A: float4 loads, 8-way plane-split + LDS reduce.
//  - k_apply: nontemporal stores for the write-once output.
// ---------------------------------------------------------------------------

typedef __bf16 bf16x8 __attribute__((ext_vector_type(8)));
typedef __bf16 bf16x4 __attribute__((ext_vector_type(4)));
typedef float f32x4 __attribute__((ext_vector_type(4)));
typedef unsigned short ushortx8 __attribute__((ext_vector_type(8)));

#define LSTR 136  // LDS row stride (elements): 128 cols (112 real + 16 zero pad) + 8 pad

__device__ __forceinline__ bf16x8 ldfrag(const unsigned short* p) {
    return __builtin_bit_cast(bf16x8, *reinterpret_cast<const ushortx8*>(p));
}

// ---------------------------------------------------------------------------
// Kernel 1: per-(tensor, channel) partial Gram (128x128 over K=784) + channel
// means. grid = 512 (tensor*256 + channel), block = 256 (4 waves).
// Wave w computes rows [32w, 32w+32) x cols [0,128) via 16x16x32 bf16 MFMA.
// Pipeline per K-tile t: convert+write(t) | sync | prefetch(t+1) ; MFMA(t) | sync
// so the 14 global loads per thread for t+1 stay in flight under the MFMA
// phase and are drained by the compiler's vmcnt(0) at the trailing barrier.
// ---------------------------------------------------------------------------
__global__ __launch_bounds__(256, 2) void k_gram(
    const float* __restrict__ student, const float* __restrict__ teacher,
    float* __restrict__ partials,   // [128 m][512 plane][128 n] fp32 (in d_out)
    float* __restrict__ y_ws)       // [2][128][256] fp32
{
    const int blk = blockIdx.x;
    const int tensor = blk >> 8;
    const int ch = blk & 255;
    const float* __restrict__ src = tensor ? teacher : student;

    const int tid = threadIdx.x;
    const int wave = tid >> 6;
    const int lane = tid & 63;
    const int mrow = lane & 15;           // MFMA row/col within 16-tile
    const int koff = (lane >> 4) * 8;     // k offset of this lane's 8 elements

    __shared__ unsigned short lds[128 * LSTR];

    const int r = tid >> 1;               // staging row 0..127
    const int half = tid & 1;             // which half (56 floats) of the 112-col tile

    // zero the k-pad columns [112,128) once (4th k-step reads them)
    {
        ushortx8 zz = {0, 0, 0, 0, 0, 0, 0, 0};
        *reinterpret_cast<ushortx8*>(&lds[r * LSTR + 112 + 8 * half]) = zz;
    }

    const float4* srow = reinterpret_cast<const float4*>(
        src + (size_t)r * 200704 + (size_t)ch * 784 + half * 56);
    unsigned short* dst = &lds[r * LSTR + half * 56];

    f32x4 acc[2][8];
    f32x4 zv = {0.f, 0.f, 0.f, 0.f};
#pragma unroll
    for (int a = 0; a < 2; ++a)
#pragma unroll
        for (int b = 0; b < 8; ++b) acc[a][b] = zv;

    float msum = 0.f;

    // prologue: tile 0 into registers
    float4 v[14];
#pragma unroll
    for (int j = 0; j < 14; ++j) v[j] = srow[j];

    for (int t = 0; t < 7; ++t) {
        // convert + write tile t (regs -> LDS); compiler emits v_cvt_pk_bf16_f32
#pragma unroll
        for (int j = 0; j < 14; ++j) {
            float4 w = v[j];
            msum += (w.x + w.y) + (w.z + w.w);
            bf16x4 hv = {(__bf16)w.x, (__bf16)w.y, (__bf16)w.z, (__bf16)w.w};
            *reinterpret_cast<bf16x4*>(dst + 4 * j) = hv;
        }
        __syncthreads();  // LDS(t) visible to all waves (pad zeros too on t=0)

        // prefetch tile t+1: issued before the MFMA phase, consumed after the
        // trailing barrier -> HBM latency hides under ds_read + MFMA.
        if (t < 6) {
#pragma unroll
            for (int j = 0; j < 14; ++j) v[j] = srow[(t + 1) * 28 + j];
        }

#pragma unroll
        for (int kk = 0; kk < 4; ++kk) {
            const int col = kk * 32 + koff;
            bf16x8 a0 = ldfrag(&lds[(32 * wave + mrow) * LSTR + col]);
            bf16x8 a1 = ldfrag(&lds[(32 * wave + 16 + mrow) * LSTR + col]);
#pragma unroll
            for (int nt = 0; nt < 8; ++nt) {
                bf16x8 bb = ldfrag(&lds[(16 * nt + mrow) * LSTR + col]);
                acc[0][nt] = __builtin_amdgcn_mfma_f32_16x16x32_bf16(a0, bb, acc[0][nt], 0, 0, 0);
                acc[1][nt] = __builtin_amdgcn_mfma_f32_16x16x32_bf16(a1, bb, acc[1][nt], 0, 0, 0);
            }
        }
        __syncthreads();  // MFMA(t) done before LDS overwrite; drains prefetch
    }

    // channel mean: pair (2r, 2r+1) holds the two halves of row r
    float other = __shfl_xor(msum, 1);
    if (half == 0)
        y_ws[tensor * 32768 + r * 256 + ch] = (msum + other) * (1.f / 784.f);

    // store partial Gram, layout [m][plane=blk][n]; C/D: col = lane&15,
    // row = (lane>>4)*4 + reg. Same 64-B-segment coalescing as before.
    const int crow = (lane >> 4) * 4;
    const int ccol = lane & 15;
    const size_t blkoff = (size_t)blk * 128;
#pragma unroll
    for (int rt = 0; rt < 2; ++rt)
#pragma unroll
        for (int nt = 0; nt < 8; ++nt)
#pragma unroll
            for (int g = 0; g < 4; ++g) {
                int m = 32 * wave + 16 * rt + crow + g;
                int n = 16 * nt + ccol;
                partials[((size_t)m << 16) + blkoff + n] = acc[rt][nt][g];
            }
}

// ---------------------------------------------------------------------------
// Kernel 2: per batch-row b: reduce partials -> G rows, normalize, z = Gn@y,
// 6 MLPs, gates. grid = 128, block = 256.
// Phase A reads one contiguous 256 KB slab ([b][512 planes][128 cols])
// as float4, split 8 ways over planes, LDS tree-reduce.
// ---------------------------------------------------------------------------
__device__ __forceinline__ float sigm(float x) { return 1.f / (1.f + __expf(-x)); }

__device__ __forceinline__ float dotf4(const float* a, const float* __restrict__ b, int n4) {
    const float4* a4 = reinterpret_cast<const float4*>(a);
    const float4* b4 = reinterpret_cast<const float4*>(b);
    float s = 0.f;
    for (int d = 0; d < n4; ++d) {
        float4 x = a4[d], y = b4[d];
        s += x.x * y.x + x.y * y.y + x.z * y.z + x.w * y.w;
    }
    return s;
}

__global__ __launch_bounds__(256) void k_gates(
    const float* __restrict__ partials, const float* __restrict__ y_ws,
    float* __restrict__ gates,
    const float* __restrict__ fs_w1, const float* __restrict__ fs_b1,
    const float* __restrict__ fs_w2, const float* __restrict__ fs_b2,
    const float* __restrict__ fsa_w1, const float* __restrict__ fsa_b1,
    const float* __restrict__ fsa_w2, const float* __restrict__ fsa_b2,
    const float* __restrict__ fsm_w1, const float* __restrict__ fsm_b1,
    const float* __restrict__ fsm_w2, const float* __restrict__ fsm_b2,
    const float* __restrict__ ft_w1, const float* __restrict__ ft_b1,
    const float* __restrict__ ft_w2, const float* __restrict__ ft_b2,
    const float* __restrict__ fta_w1, const float* __restrict__ fta_b1,
    const float* __restrict__ fta_w2, const float* __restrict__ fta_b2,
    const float* __restrict__ ftm_w1, const float* __restrict__ ftm_b1,
    const float* __restrict__ ftm_w2, const float* __restrict__ ftm_b2)
{
    const int b = blockIdx.x;
    const int tid = threadIdx.x;
    const int wave = tid >> 6;
    const int lane = tid & 63;

    __shared__ __align__(16) float Gn[2][128];
    __shared__ float wred[4];
    __shared__ __align__(16) float z[512];
    __shared__ __align__(16) float za[256];
    __shared__ __align__(16) float zm[256];
    __shared__ __align__(16) float hbuf[256];   // hS[0:128) | hT[128:256)
    __shared__ __align__(16) float h2buf[256];  // hSA | hTA | hSM | hTM (64 each)
    __shared__ __align__(16) float red[8][128]; // plane-group partial sums

    // --- phase A: reduce G row b over 512 planes (contiguous 256 KB slab) ---
    {
        const int pg = tid >> 5;      // plane group 0..7 (64 planes each)
        const int jq = tid & 31;      // float4 column group 0..31
        const float4* pb4 = reinterpret_cast<const float4*>(partials + ((size_t)b << 16))
                            + (size_t)(pg * 64) * 32 + jq;
        float4 s = {0.f, 0.f, 0.f, 0.f};
#pragma unroll 8
        for (int p = 0; p < 64; ++p) {
            float4 vv = pb4[p * 32];
            s.x += vv.x; s.y += vv.y; s.z += vv.z; s.w += vv.w;
        }
        *reinterpret_cast<float4*>(&red[pg][jq * 4]) = s;
    }
    __syncthreads();

    const int tt = tid >> 7;          // tensor (pg 0..3 = s, 4..7 = t)
    const int j = tid & 127;
    float g = (red[tt * 4 + 0][j] + red[tt * 4 + 1][j]) +
              (red[tt * 4 + 2][j] + red[tt * 4 + 3][j]);

    // row norm: waves 0,1 -> tensor s; waves 2,3 -> tensor t
    float v2 = g * g;
#pragma unroll
    for (int off = 32; off > 0; off >>= 1) v2 += __shfl_xor(v2, off);
    if (lane == 0) wred[wave] = v2;
    __syncthreads();
    float ss = tt ? (wred[2] + wred[3]) : (wred[0] + wred[1]);
    float inv = 1.f / fmaxf(sqrtf(ss), 1e-12f);
    Gn[tt][j] = g * inv;
    __syncthreads();

    // --- phase B: zs/zt[c] = sum_j Gn[j] * y[j][c] ---
    const int c = tid;
    float zs = 0.f, zt = 0.f;
    const float* ys = y_ws;
    const float* yt = y_ws + 32768;
    for (int jj = 0; jj < 128; ++jj) {
        zs = fmaf(Gn[0][jj], ys[jj * 256 + c], zs);
        zt = fmaf(Gn[1][jj], yt[jj * 256 + c], zt);
    }
    z[c] = zs;
    z[256 + c] = zt;
    za[c] = zs + zt;
    zm[c] = zs * zt;
    __syncthreads();

    // --- hidden layers ---
    {   // fc_s (threads 0..127) / fc_t (128..255): din=512, dh=128
        const int h = tid & 127;
        const float* w = (tid < 128) ? (fs_w1 + h * 512) : (ft_w1 + h * 512);
        const float* bb = (tid < 128) ? fs_b1 : ft_b1;
        hbuf[tid] = fmaxf(bb[h] + dotf4(z, w, 128), 0.f);
    }
    {   // fc_s_add / fc_t_add / fc_s_mul / fc_t_mul: din=256, dh=64
        const int q = tid >> 6;
        const int i = tid & 63;
        const float* w = (q == 0) ? fsa_w1 : (q == 1) ? fta_w1 : (q == 2) ? fsm_w1 : ftm_w1;
        const float* bb = (q == 0) ? fsa_b1 : (q == 1) ? fta_b1 : (q == 2) ? fsm_b1 : ftm_b1;
        const float* in = (q < 2) ? za : zm;
        h2buf[tid] = fmaxf(bb[i] + dotf4(in, w + i * 256, 64), 0.f);
    }
    __syncthreads();

    // --- output layers + gates (dout=256, every thread one channel) ---
    {
        float gs  = sigm(fs_b2[c]  + dotf4(hbuf,        fs_w2  + c * 128, 32));
        float gt  = sigm(ft_b2[c]  + dotf4(hbuf + 128,  ft_w2  + c * 128, 32));
        float gsa = sigm(fsa_b2[c] + dotf4(h2buf,       fsa_w2 + c * 64, 16));
        float gta = sigm(fta_b2[c] + dotf4(h2buf + 64,  fta_w2 + c * 64, 16));
        float gsm = sigm(fsm_b2[c] + dotf4(h2buf + 128, fsm_w2 + c * 64, 16));
        float gtm = sigm(ftm_b2[c] + dotf4(h2buf + 192, ftm_w2 + c * 64, 16));
        gates[b * 256 + c] = gs + gsa + gsm;
        gates[32768 + b * 256 + c] = gt + gta + gtm;
    }
}

// ---------------------------------------------------------------------------
// Kernel 3: out = gate[b,c] * input, float4 + nontemporal store.
// grid = 50176, block = 256.
// ---------------------------------------------------------------------------
__global__ __launch_bounds__(256) void k_apply(
    const float4* __restrict__ student4, const float4* __restrict__ teacher4,
    const float* __restrict__ gates, float* __restrict__ out)
{
    const unsigned i = blockIdx.x * 256u + threadIdx.x;   // < 12845056
    const unsigned PER = 6422528u;                        // float4s per tensor
    const unsigned isT = (i >= PER) ? 1u : 0u;
    const unsigned jj = i - isT * PER;
    const unsigned bc = jj / 196u;                        // 196 float4 per (b,c) plane
    const float g = gates[isT * 32768u + bc];
    const float4* in = isT ? teacher4 : student4;
    float4 v = in[jj];
    f32x4 r = {v.x * g, v.y * g, v.z * g, v.w * g};
    __builtin_nontemporal_store(r, reinterpret_cast<f32x4*>(out) + i);
}

// ---------------------------------------------------------------------------
extern "C" void kernel_launch(void* const* d_in, const int* in_sizes, int n_in,
                              void* d_out, int out_size, void* d_ws, size_t ws_size,
                              hipStream_t stream) {
    (void)in_sizes; (void)n_in; (void)out_size; (void)ws_size;

    const float* student = (const float*)d_in[0];
    const float* teacher = (const float*)d_in[1];
    const float* fs_w1  = (const float*)d_in[2];
    const float* fs_b1  = (const float*)d_in[3];
    const float* fs_w2  = (const float*)d_in[4];
    const float* fs_b2  = (const float*)d_in[5];
    const float* fsa_w1 = (const float*)d_in[6];
    const float* fsa_b1 = (const float*)d_in[7];
    const float* fsa_w2 = (const float*)d_in[8];
    const float* fsa_b2 = (const float*)d_in[9];
    const float* fsm_w1 = (const float*)d_in[10];
    const float* fsm_b1 = (const float*)d_in[11];
    const float* fsm_w2 = (const float*)d_in[12];
    const float* fsm_b2 = (const float*)d_in[13];
    const float* ft_w1  = (const float*)d_in[14];
    const float* ft_b1  = (const float*)d_in[15];
    const float* ft_w2  = (const float*)d_in[16];
    const float* ft_b2  = (const float*)d_in[17];
    const float* fta_w1 = (const float*)d_in[18];
    const float* fta_b1 = (const float*)d_in[19];
    const float* fta_w2 = (const float*)d_in[20];
    const float* fta_b2 = (const float*)d_in[21];
    const float* ftm_w1 = (const float*)d_in[22];
    const float* ftm_b1 = (const float*)d_in[23];
    const float* ftm_w2 = (const float*)d_in[24];
    const float* ftm_b2 = (const float*)d_in[25];

    float* out = (float*)d_out;
    float* partials = out;                  // 128*512*128 fp32 = 33.5 MB, scratch in d_out
    float* y_ws = (float*)d_ws;             // 65536 fp32
    float* gates = y_ws + 65536;            // 65536 fp32

    k_gram<<<dim3(512), dim3(256), 0, stream>>>(student, teacher, partials, y_ws);
    k_gates<<<dim3(128), dim3(256), 0, stream>>>(partials, y_ws, gates,
        fs_w1, fs_b1, fs_w2, fs_b2,
        fsa_w1, fsa_b1, fsa_w2, fsa_b2,
        fsm_w1, fsm_b1, fsm_w2, fsm_b2,
        ft_w1, ft_b1, ft_w2, ft_b2,
        fta_w1, fta_b1, fta_w2, fta_b2,
        ftm_w1, ftm_b1, ftm_w2, ftm_b2);
    k_apply<<<dim3(50176), dim3(256), 0, stream>>>(
        (const float4*)student, (const float4*)teacher, gates, out);
}

// Round 4
// 476.969 us; speedup vs baseline: 1.0242x; 1.0047x over previous
//
#include <hip/hip_runtime.h>

// ---------------------------------------------------------------------------
// SE_semantic_Fusion: G = fm@fm.T (bf16 MFMA, split-K over channels),
// row-normalize, z = Gn@y, 6 tiny MLPs -> gates, out = gate * input.
// d_out doubles as scratch for the Gram partials (k_apply overwrites all of
// d_out last); d_ws holds only y (256KB) + gates (256KB).
//
// R4 changes vs R3 (479 us):
//  - k_gram split-K 512 -> 256 blocks (2 channels per block, accumulated in
//    the same acc regs): partials traffic halves (33.5 -> 16.8 MB each way).
//  - k_gram double-buffered LDS, ONE barrier per K-tile (was 2): per tile,
//    issue loads(t+2) -> cvt+write(t+1 -> other buf) -> MFMA(t) -> barrier.
//    Loads stream ~2 tiles ahead; no full vmcnt(0) drain mid-tile.
//  - k_gates phase A adjusted to 256 planes (128 KB slab per row).
// ---------------------------------------------------------------------------

typedef __bf16 bf16x8 __attribute__((ext_vector_type(8)));
typedef __bf16 bf16x4 __attribute__((ext_vector_type(4)));
typedef float f32x4 __attribute__((ext_vector_type(4)));
typedef unsigned short ushortx8 __attribute__((ext_vector_type(8)));

#define LSTR 136  // LDS row stride (elements): 128 cols (112 real + 16 zero pad) + 8 pad

__device__ __forceinline__ bf16x8 ldfrag(const unsigned short* p) {
    return __builtin_bit_cast(bf16x8, *reinterpret_cast<const ushortx8*>(p));
}

// ---------------------------------------------------------------------------
// Kernel 1: per-(tensor, channel-pair) partial Gram (128x128 over 2x784) +
// channel means. grid = 256 (tensor*128 + chpair), block = 256 (4 waves).
// Wave w computes rows [32w, 32w+32) x cols [0,128) via 16x16x32 bf16 MFMA.
// 14 K-tiles (7 per channel), double-buffered LDS, 1 barrier/tile.
// ---------------------------------------------------------------------------
__global__ __launch_bounds__(256, 1) void k_gram(
    const float* __restrict__ student, const float* __restrict__ teacher,
    float* __restrict__ partials,   // [128 m][256 plane][128 n] fp32 (in d_out)
    float* __restrict__ y_ws)       // [2][128][256] fp32
{
    const int blk = blockIdx.x;           // [0,256)
    const int tensor = blk >> 7;
    const int chpair = blk & 127;         // channels {2*chpair, 2*chpair+1}
    const float* __restrict__ src = tensor ? teacher : student;

    const int tid = threadIdx.x;
    const int wave = tid >> 6;
    const int lane = tid & 63;
    const int mrow = lane & 15;           // MFMA row/col within 16-tile
    const int koff = (lane >> 4) * 8;     // k offset of this lane's 8 elements

    __shared__ unsigned short lds[2][128 * LSTR];

    const int r = tid >> 1;               // staging row 0..127
    const int half = tid & 1;             // which half (56 floats) of the 112-col tile

    // zero the k-pad columns [112,128) in BOTH buffers once
    {
        ushortx8 zz = {0, 0, 0, 0, 0, 0, 0, 0};
        *reinterpret_cast<ushortx8*>(&lds[0][r * LSTR + 112 + 8 * half]) = zz;
        *reinterpret_cast<ushortx8*>(&lds[1][r * LSTR + 112 + 8 * half]) = zz;
    }

    const float4* s0 = reinterpret_cast<const float4*>(
        src + (size_t)r * 200704 + (size_t)(2 * chpair) * 784 + half * 56);
    const float4* s1 = reinterpret_cast<const float4*>(
        src + (size_t)r * 200704 + (size_t)(2 * chpair + 1) * 784 + half * 56);
    unsigned short* dst0 = &lds[0][r * LSTR + half * 56];
    unsigned short* dst1 = &lds[1][r * LSTR + half * 56];

    f32x4 acc[2][8];
    f32x4 zv = {0.f, 0.f, 0.f, 0.f};
#pragma unroll
    for (int a = 0; a < 2; ++a)
#pragma unroll
        for (int b = 0; b < 8; ++b) acc[a][b] = zv;

    float msum0 = 0.f, msum1 = 0.f;       // per-channel mean accumulators

    float4 vE[14], vO[14];                // even-slot / odd-slot load regs

    // tile t in [0,14): channel = t<7 ? ch0 : ch1, sub-tile tc = t%7
#define ISSUE(vv, t)                                                        \
    {                                                                       \
        const float4* base_ = ((t) < 7 ? s0 : s1) + ((t) < 7 ? (t) : (t)-7) * 28; \
        _Pragma("unroll")                                                   \
        for (int j = 0; j < 14; ++j) (vv)[j] = base_[j];                    \
    }

#define CVTW(vv, dstp, t)                                                   \
    {                                                                       \
        float* ms_ = ((t) < 7) ? &msum0 : &msum1;                           \
        _Pragma("unroll")                                                   \
        for (int j = 0; j < 14; ++j) {                                      \
            float4 w = (vv)[j];                                             \
            *ms_ += (w.x + w.y) + (w.z + w.w);                              \
            bf16x4 hv = {(__bf16)w.x, (__bf16)w.y, (__bf16)w.z, (__bf16)w.w}; \
            *reinterpret_cast<bf16x4*>((dstp) + 4 * j) = hv;                \
        }                                                                   \
    }

#define MFMA_TILE(buf)                                                      \
    {                                                                       \
        const unsigned short* b_ = (buf);                                   \
        _Pragma("unroll")                                                   \
        for (int kk = 0; kk < 4; ++kk) {                                    \
            const int col = kk * 32 + koff;                                 \
            bf16x8 a0 = ldfrag(&b_[(32 * wave + mrow) * LSTR + col]);       \
            bf16x8 a1 = ldfrag(&b_[(32 * wave + 16 + mrow) * LSTR + col]);  \
            _Pragma("unroll")                                               \
            for (int nt = 0; nt < 8; ++nt) {                                \
                bf16x8 bb = ldfrag(&b_[(16 * nt + mrow) * LSTR + col]);     \
                acc[0][nt] = __builtin_amdgcn_mfma_f32_16x16x32_bf16(a0, bb, acc[0][nt], 0, 0, 0); \
                acc[1][nt] = __builtin_amdgcn_mfma_f32_16x16x32_bf16(a1, bb, acc[1][nt], 0, 0, 0); \
            }                                                               \
        }                                                                   \
    }

    // prologue: tiles 0,1 in flight; write tile 0 into buf0
    ISSUE(vE, 0);
    ISSUE(vO, 1);
    CVTW(vE, dst0, 0);
    __syncthreads();   // buf0 + pad zeros (both bufs) visible

#pragma unroll
    for (int tp = 0; tp < 14; tp += 2) {
        // even tile tp: compute from buf0; stage tile tp+1 into buf1
        if (tp + 2 < 14) ISSUE(vE, tp + 2);
        CVTW(vO, dst1, tp + 1);
        MFMA_TILE(&lds[0][0]);
        __syncthreads();
        // odd tile tp+1: compute from buf1; stage tile tp+2 into buf0
        if (tp + 3 < 14) ISSUE(vO, tp + 3);
        if (tp + 2 < 14) CVTW(vE, dst0, tp + 2);
        MFMA_TILE(&lds[1][0]);
        __syncthreads();
    }
#undef ISSUE
#undef CVTW
#undef MFMA_TILE

    // channel means: pair (2r, 2r+1) holds the two halves of row r
    float o0 = __shfl_xor(msum0, 1);
    float o1 = __shfl_xor(msum1, 1);
    if (half == 0) {
        y_ws[tensor * 32768 + r * 256 + 2 * chpair]     = (msum0 + o0) * (1.f / 784.f);
        y_ws[tensor * 32768 + r * 256 + 2 * chpair + 1] = (msum1 + o1) * (1.f / 784.f);
    }

    // store partial Gram, layout [m][plane=blk][n]; C/D: col = lane&15,
    // row = (lane>>4)*4 + reg.
    const int crow = (lane >> 4) * 4;
    const int ccol = lane & 15;
    const size_t blkoff = (size_t)blk * 128;
#pragma unroll
    for (int rt = 0; rt < 2; ++rt)
#pragma unroll
        for (int nt = 0; nt < 8; ++nt)
#pragma unroll
            for (int g = 0; g < 4; ++g) {
                int m = 32 * wave + 16 * rt + crow + g;
                int n = 16 * nt + ccol;
                partials[((size_t)m << 15) + blkoff + n] = acc[rt][nt][g];
            }
}

// ---------------------------------------------------------------------------
// Kernel 2: per batch-row b: reduce partials -> G rows, normalize, z = Gn@y,
// 6 MLPs, gates. grid = 128, block = 256.
// Phase A reads one contiguous 128 KB slab ([b][256 planes][128 cols])
// as float4, split 8 ways over planes, LDS tree-reduce.
// ---------------------------------------------------------------------------
__device__ __forceinline__ float sigm(float x) { return 1.f / (1.f + __expf(-x)); }

__device__ __forceinline__ float dotf4(const float* a, const float* __restrict__ b, int n4) {
    const float4* a4 = reinterpret_cast<const float4*>(a);
    const float4* b4 = reinterpret_cast<const float4*>(b);
    float s = 0.f;
    for (int d = 0; d < n4; ++d) {
        float4 x = a4[d], y = b4[d];
        s += x.x * y.x + x.y * y.y + x.z * y.z + x.w * y.w;
    }
    return s;
}

__global__ __launch_bounds__(256) void k_gates(
    const float* __restrict__ partials, const float* __restrict__ y_ws,
    float* __restrict__ gates,
    const float* __restrict__ fs_w1, const float* __restrict__ fs_b1,
    const float* __restrict__ fs_w2, const float* __restrict__ fs_b2,
    const float* __restrict__ fsa_w1, const float* __restrict__ fsa_b1,
    const float* __restrict__ fsa_w2, const float* __restrict__ fsa_b2,
    const float* __restrict__ fsm_w1, const float* __restrict__ fsm_b1,
    const float* __restrict__ fsm_w2, const float* __restrict__ fsm_b2,
    const float* __restrict__ ft_w1, const float* __restrict__ ft_b1,
    const float* __restrict__ ft_w2, const float* __restrict__ ft_b2,
    const float* __restrict__ fta_w1, const float* __restrict__ fta_b1,
    const float* __restrict__ fta_w2, const float* __restrict__ fta_b2,
    const float* __restrict__ ftm_w1, const float* __restrict__ ftm_b1,
    const float* __restrict__ ftm_w2, const float* __restrict__ ftm_b2)
{
    const int b = blockIdx.x;
    const int tid = threadIdx.x;
    const int wave = tid >> 6;
    const int lane = tid & 63;

    __shared__ __align__(16) float Gn[2][128];
    __shared__ float wred[4];
    __shared__ __align__(16) float z[512];
    __shared__ __align__(16) float za[256];
    __shared__ __align__(16) float zm[256];
    __shared__ __align__(16) float hbuf[256];   // hS[0:128) | hT[128:256)
    __shared__ __align__(16) float h2buf[256];  // hSA | hTA | hSM | hTM (64 each)
    __shared__ __align__(16) float red[8][128]; // plane-group partial sums

    // --- phase A: reduce G row b over 256 planes (contiguous 128 KB slab) ---
    {
        const int pg = tid >> 5;      // plane group 0..7 (32 planes each)
        const int jq = tid & 31;      // float4 column group 0..31
        const float4* pb4 = reinterpret_cast<const float4*>(partials)
                            + (size_t)b * 8192 + pg * 1024 + jq;
        float4 s = {0.f, 0.f, 0.f, 0.f};
#pragma unroll 8
        for (int p = 0; p < 32; ++p) {
            float4 vv = pb4[p * 32];
            s.x += vv.x; s.y += vv.y; s.z += vv.z; s.w += vv.w;
        }
        *reinterpret_cast<float4*>(&red[pg][jq * 4]) = s;
    }
    __syncthreads();

    const int tt = tid >> 7;          // tensor (pg 0..3 = s, 4..7 = t)
    const int j = tid & 127;
    float g = (red[tt * 4 + 0][j] + red[tt * 4 + 1][j]) +
              (red[tt * 4 + 2][j] + red[tt * 4 + 3][j]);

    // row norm: waves 0,1 -> tensor s; waves 2,3 -> tensor t
    float v2 = g * g;
#pragma unroll
    for (int off = 32; off > 0; off >>= 1) v2 += __shfl_xor(v2, off);
    if (lane == 0) wred[wave] = v2;
    __syncthreads();
    float ss = tt ? (wred[2] + wred[3]) : (wred[0] + wred[1]);
    float inv = 1.f / fmaxf(sqrtf(ss), 1e-12f);
    Gn[tt][j] = g * inv;
    __syncthreads();

    // --- phase B: zs/zt[c] = sum_j Gn[j] * y[j][c] ---
    const int c = tid;
    float zs = 0.f, zt = 0.f;
    const float* ys = y_ws;
    const float* yt = y_ws + 32768;
    for (int jj = 0; jj < 128; ++jj) {
        zs = fmaf(Gn[0][jj], ys[jj * 256 + c], zs);
        zt = fmaf(Gn[1][jj], yt[jj * 256 + c], zt);
    }
    z[c] = zs;
    z[256 + c] = zt;
    za[c] = zs + zt;
    zm[c] = zs * zt;
    __syncthreads();

    // --- hidden layers ---
    {   // fc_s (threads 0..127) / fc_t (128..255): din=512, dh=128
        const int h = tid & 127;
        const float* w = (tid < 128) ? (fs_w1 + h * 512) : (ft_w1 + h * 512);
        const float* bb = (tid < 128) ? fs_b1 : ft_b1;
        hbuf[tid] = fmaxf(bb[h] + dotf4(z, w, 128), 0.f);
    }
    {   // fc_s_add / fc_t_add / fc_s_mul / fc_t_mul: din=256, dh=64
        const int q = tid >> 6;
        const int i = tid & 63;
        const float* w = (q == 0) ? fsa_w1 : (q == 1) ? fta_w1 : (q == 2) ? fsm_w1 : ftm_w1;
        const float* bb = (q == 0) ? fsa_b1 : (q == 1) ? fta_b1 : (q == 2) ? fsm_b1 : ftm_b1;
        const float* in = (q < 2) ? za : zm;
        h2buf[tid] = fmaxf(bb[i] + dotf4(in, w + i * 256, 64), 0.f);
    }
    __syncthreads();

    // --- output layers + gates (dout=256, every thread one channel) ---
    {
        float gs  = sigm(fs_b2[c]  + dotf4(hbuf,        fs_w2  + c * 128, 32));
        float gt  = sigm(ft_b2[c]  + dotf4(hbuf + 128,  ft_w2  + c * 128, 32));
        float gsa = sigm(fsa_b2[c] + dotf4(h2buf,       fsa_w2 + c * 64, 16));
        float gta = sigm(fta_b2[c] + dotf4(h2buf + 64,  fta_w2 + c * 64, 16));
        float gsm = sigm(fsm_b2[c] + dotf4(h2buf + 128, fsm_w2 + c * 64, 16));
        float gtm = sigm(ftm_b2[c] + dotf4(h2buf + 192, ftm_w2 + c * 64, 16));
        gates[b * 256 + c] = gs + gsa + gsm;
        gates[32768 + b * 256 + c] = gt + gta + gtm;
    }
}

// ---------------------------------------------------------------------------
// Kernel 3: out = gate[b,c] * input, float4 + nontemporal store.
// grid = 50176, block = 256.
// ---------------------------------------------------------------------------
__global__ __launch_bounds__(256) void k_apply(
    const float4* __restrict__ student4, const float4* __restrict__ teacher4,
    const float* __restrict__ gates, float* __restrict__ out)
{
    const unsigned i = blockIdx.x * 256u + threadIdx.x;   // < 12845056
    const unsigned PER = 6422528u;                        // float4s per tensor
    const unsigned isT = (i >= PER) ? 1u : 0u;
    const unsigned jj = i - isT * PER;
    const unsigned bc = jj / 196u;                        // 196 float4 per (b,c) plane
    const float g = gates[isT * 32768u + bc];
    const float4* in = isT ? teacher4 : student4;
    float4 v = in[jj];
    f32x4 r = {v.x * g, v.y * g, v.z * g, v.w * g};
    __builtin_nontemporal_store(r, reinterpret_cast<f32x4*>(out) + i);
}

// ---------------------------------------------------------------------------
extern "C" void kernel_launch(void* const* d_in, const int* in_sizes, int n_in,
                              void* d_out, int out_size, void* d_ws, size_t ws_size,
                              hipStream_t stream) {
    (void)in_sizes; (void)n_in; (void)out_size; (void)ws_size;

    const float* student = (const float*)d_in[0];
    const float* teacher = (const float*)d_in[1];
    const float* fs_w1  = (const float*)d_in[2];
    const float* fs_b1  = (const float*)d_in[3];
    const float* fs_w2  = (const float*)d_in[4];
    const float* fs_b2  = (const float*)d_in[5];
    const float* fsa_w1 = (const float*)d_in[6];
    const float* fsa_b1 = (const float*)d_in[7];
    const float* fsa_w2 = (const float*)d_in[8];
    const float* fsa_b2 = (const float*)d_in[9];
    const float* fsm_w1 = (const float*)d_in[10];
    const float* fsm_b1 = (const float*)d_in[11];
    const float* fsm_w2 = (const float*)d_in[12];
    const float* fsm_b2 = (const float*)d_in[13];
    const float* ft_w1  = (const float*)d_in[14];
    const float* ft_b1  = (const float*)d_in[15];
    const float* ft_w2  = (const float*)d_in[16];
    const float* ft_b2  = (const float*)d_in[17];
    const float* fta_w1 = (const float*)d_in[18];
    const float* fta_b1 = (const float*)d_in[19];
    const float* fta_w2 = (const float*)d_in[20];
    const float* fta_b2 = (const float*)d_in[21];
    const float* ftm_w1 = (const float*)d_in[22];
    const float* ftm_b1 = (const float*)d_in[23];
    const float* ftm_w2 = (const float*)d_in[24];
    const float* ftm_b2 = (const float*)d_in[25];

    float* out = (float*)d_out;
    float* partials = out;                  // 128*256*128 fp32 = 16.8 MB, scratch in d_out
    float* y_ws = (float*)d_ws;             // 65536 fp32
    float* gates = y_ws + 65536;            // 65536 fp32

    k_gram<<<dim3(256), dim3(256), 0, stream>>>(student, teacher, partials, y_ws);
    k_gates<<<dim3(128), dim3(256), 0, stream>>>(partials, y_ws, gates,
        fs_w1, fs_b1, fs_w2, fs_b2,
        fsa_w1, fsa_b1, fsa_w2, fsa_b2,
        fsm_w1, fsm_b1, fsm_w2, fsm_b2,
        ft_w1, ft_b1, ft_w2, ft_b2,
        fta_w1, fta_b1, fta_w2, fta_b2,
        ftm_w1, ftm_b1, ftm_w2, ftm_b2);
    k_apply<<<dim3(50176), dim3(256), 0, stream>>>(
        (const float4*)student, (const float4*)teacher, gates, out);
}